// Round 12
// baseline (102.620 us; speedup 1.0000x reference)
//
#include <hip/hip_runtime.h>
#include <math.h>

// CandidateAwareClock: per row b
//   q = emb[cand[b]]; k_l = emb[items[b,l]]
//   logits_l = dot(k_l,q) * gate[dts[b,l]] / tau   (gate row 0 == 0)
//   masked softmax over l -> attn; u = sum_l attn_l * k_l
//   tau = softplus(raw_tau) + 1e-6
// Outputs concatenated: u [B*64], attn [B*200], tau [1]
//
// R12: R9's single-pass online-softmax (one wave per row, zero barriers),
// widened and software-pipelined:
//  - 32 entries per iteration (lane quad r handles entries e=g*32+r and
//    e+16; same j => both feed the same acc dims) -> 8 loads/iter in flight,
//    shuffle-max chain amortized over 2x entries, ~4 iters instead of ~7
//  - explicit double-buffer prefetch: group g+1's meta+kv loads issue
//    before group g's compute -> load latency hides under VALU chain
// ~110 VGPR; grid-limited 4 waves/SIMD so VGPR<=128 is free.

constexpr int Bsz  = 4096;
constexpr int Lseq = 200;
constexpr int Dim  = 64;
constexpr int WPB  = 4;     // waves per block; one batch row per wave

__global__ __launch_bounds__(256, 2)
void cac_kernel(const int* __restrict__ items,
                const int* __restrict__ dts,
                const int* __restrict__ mask,
                const int* __restrict__ cand,
                const float* __restrict__ emb,
                const float* __restrict__ gate,
                const float* __restrict__ rawtau,
                float* __restrict__ out_u,
                float* __restrict__ out_attn,
                float* __restrict__ out_tau)
{
    __shared__ int   cpos[WPB][Lseq];    // compacted -> original position
    __shared__ int   crow[WPB][Lseq];    // compacted -> item row
    __shared__ float cgate[WPB][Lseq];   // compacted -> gate value
    __shared__ float clog[WPB][Lseq];    // compacted -> logit (for attn out)

    const int tid  = threadIdx.x;
    const int wv   = tid >> 6;
    const int lane = tid & 63;
    const int b    = blockIdx.x * WPB + wv;

    // tau
    const float raw = rawtau[0];
    const float sp  = (raw > 20.f) ? raw : log1pf(expf(raw));
    const float tau = sp + 1e-6f;
    const float inv_tau = 1.0f / tau;
    if (b == 0 && tid == 0) out_tau[0] = tau;

    // per-lane loads for 4 position chunks (p = 64k + lane)
    int rowk[4], mk[4];
    float gk[4];
    #pragma unroll
    for (int k = 0; k < 4; ++k) {
        const int  p  = k * 64 + lane;
        const bool in = (p < Lseq);
        rowk[k] = in ? items[(size_t)b * Lseq + p] : 0;
        mk[k]   = in ? mask[(size_t)b * Lseq + p] : 0;
        const int dt = in ? dts[(size_t)b * Lseq + p] : 0;
        gk[k] = (dt == 0) ? 0.f : gate[dt];          // padding_idx=0
    }

    // ---- in-wave ballot compaction (no barriers) ----
    unsigned long long bals[4];
    int offs[5];
    offs[0] = 0;
    #pragma unroll
    for (int k = 0; k < 4; ++k) {
        bals[k] = __ballot(mk[k] != 0);
        offs[k + 1] = offs[k] + __popcll(bals[k]);
    }
    const int cnt = offs[4];                         // >=1 (mask[:,0]=True)
    const unsigned long long ltmask = (1ull << lane) - 1ull;
    #pragma unroll
    for (int k = 0; k < 4; ++k) {
        if (mk[k]) {
            const int idx = offs[k] + __popcll(bals[k] & ltmask);
            cpos[wv][idx]  = k * 64 + lane;
            crow[wv][idx]  = rowk[k];
            cgate[wv][idx] = gk[k];
        }
    }

    // q fragment: lane (r,j) holds q dims {16i+4j..+3}
    const int r = lane >> 2;
    const int j = lane & 3;
    const float4* qrow = (const float4*)(emb + (size_t)cand[b] * Dim);
    float4 qv[4];
    #pragma unroll
    for (int i = 0; i < 4; ++i) qv[i] = qrow[i * 4 + j];

    float acc[16];
    #pragma unroll
    for (int i = 0; i < 16; ++i) acc[i] = 0.f;
    float m = -INFINITY, s_l = 0.f;

    const int ngrp = (cnt + 31) >> 5;                // 32 entries per group

    // ---- prologue: load group 0 (entries r and r+16, clamped) ----
    int e0 = r, e1 = 16 + r;
    int ec0 = (e0 < cnt) ? e0 : (cnt - 1);
    int ec1 = (e1 < cnt) ? e1 : (cnt - 1);
    int   row0 = crow[wv][ec0],  row1 = crow[wv][ec1];
    float cg0  = cgate[wv][ec0], cg1  = cgate[wv][ec1];
    float4 kv0[4], kv1[4];
    {
        const float4* kp0 = (const float4*)(emb + (size_t)row0 * Dim);
        const float4* kp1 = (const float4*)(emb + (size_t)row1 * Dim);
        #pragma unroll
        for (int i = 0; i < 4; ++i) kv0[i] = kp0[i * 4 + j];
        #pragma unroll
        for (int i = 0; i < 4; ++i) kv1[i] = kp1[i * 4 + j];
    }

    for (int g = 0; g < ngrp; ++g) {
        // ---- prefetch group g+1 (clamped; last iter re-loads, L1-hot) ----
        const int gn = (g + 1 < ngrp) ? (g + 1) : g;
        const int ne0 = gn * 32 + r, ne1 = ne0 + 16;
        const int nec0 = (ne0 < cnt) ? ne0 : (cnt - 1);
        const int nec1 = (ne1 < cnt) ? ne1 : (cnt - 1);
        const int   nrow0 = crow[wv][nec0],  nrow1 = crow[wv][nec1];
        const float ncg0  = cgate[wv][nec0], ncg1  = cgate[wv][nec1];
        float4 nkv0[4], nkv1[4];
        {
            const float4* np0 = (const float4*)(emb + (size_t)nrow0 * Dim);
            const float4* np1 = (const float4*)(emb + (size_t)nrow1 * Dim);
            #pragma unroll
            for (int i = 0; i < 4; ++i) nkv0[i] = np0[i * 4 + j];
            #pragma unroll
            for (int i = 0; i < 4; ++i) nkv1[i] = np1[i * 4 + j];
        }

        // ---- compute current group (entries e0, e1) ----
        float p0 = 0.f, p1 = 0.f;
        #pragma unroll
        for (int i = 0; i < 4; ++i) {
            p0 = fmaf(kv0[i].x, qv[i].x, p0);
            p0 = fmaf(kv0[i].y, qv[i].y, p0);
            p0 = fmaf(kv0[i].z, qv[i].z, p0);
            p0 = fmaf(kv0[i].w, qv[i].w, p0);
            p1 = fmaf(kv1[i].x, qv[i].x, p1);
            p1 = fmaf(kv1[i].y, qv[i].y, p1);
            p1 = fmaf(kv1[i].z, qv[i].z, p1);
            p1 = fmaf(kv1[i].w, qv[i].w, p1);
        }
        p0 += __shfl_xor(p0, 1, 64);  p0 += __shfl_xor(p0, 2, 64);
        p1 += __shfl_xor(p1, 1, 64);  p1 += __shfl_xor(p1, 2, 64);

        const float logit0 = p0 * cg0 * inv_tau;
        const float logit1 = p1 * cg1 * inv_tau;
        const float leff0  = (e0 < cnt) ? logit0 : -INFINITY;
        const float leff1  = (e1 < cnt) ? logit1 : -INFINITY;

        float gm = fmaxf(leff0, leff1);
        #pragma unroll
        for (int off = 4; off < 64; off <<= 1)
            gm = fmaxf(gm, __shfl_xor(gm, off, 64));

        if (gm > m) {                                // wave-uniform, rare later
            const float scale = __expf(m - gm);      // m=-inf first iter -> 0
            s_l *= scale;
            #pragma unroll
            for (int i = 0; i < 16; ++i) acc[i] *= scale;
            m = gm;
        }

        const float w0 = __expf(leff0 - m);          // invalid -> 0
        const float w1 = __expf(leff1 - m);
        if (e0 < cnt && j == 0) clog[wv][e0] = logit0;
        if (e1 < cnt && j == 0) clog[wv][e1] = logit1;
        if (j == 0) s_l += w0 + w1;
        #pragma unroll
        for (int i = 0; i < 4; ++i) {
            acc[4 * i + 0] = fmaf(w0, kv0[i].x, fmaf(w1, kv1[i].x, acc[4 * i + 0]));
            acc[4 * i + 1] = fmaf(w0, kv0[i].y, fmaf(w1, kv1[i].y, acc[4 * i + 1]));
            acc[4 * i + 2] = fmaf(w0, kv0[i].z, fmaf(w1, kv1[i].z, acc[4 * i + 2]));
            acc[4 * i + 3] = fmaf(w0, kv0[i].w, fmaf(w1, kv1[i].w, acc[4 * i + 3]));
        }

        // ---- rotate buffers ----
        e0 = ne0; e1 = ne1;
        cg0 = ncg0; cg1 = ncg1;
        #pragma unroll
        for (int i = 0; i < 4; ++i) { kv0[i] = nkv0[i]; kv1[i] = nkv1[i]; }
    }

    // ---- reduce acc across the 16 r-groups (same j = same dims) ----
    #pragma unroll
    for (int off = 4; off < 64; off <<= 1) {
        #pragma unroll
        for (int i = 0; i < 16; ++i) acc[i] += __shfl_xor(acc[i], off, 64);
    }
    float s = s_l;                                   // nonzero only at j==0 lanes
    #pragma unroll
    for (int off = 1; off < 64; off <<= 1) s += __shfl_xor(s, off, 64);
    const float inv_s = 1.0f / s;

    // u write: lanes 0..3 (r==0, j=lane) each own 16 dims = 4 float4s
    if (r == 0) {
        float4* up = (float4*)(out_u + (size_t)b * Dim);
        #pragma unroll
        for (int i = 0; i < 4; ++i) {
            float4 o;
            o.x = acc[4 * i + 0] * inv_s;
            o.y = acc[4 * i + 1] * inv_s;
            o.z = acc[4 * i + 2] * inv_s;
            o.w = acc[4 * i + 3] * inv_s;
            up[i * 4 + j] = o;                       // dims 16i+4j..+3
        }
    }

    // attn: masked positions -> 0 (each position has exactly one writer)
    #pragma unroll
    for (int k = 0; k < 4; ++k) {
        const int p = k * 64 + lane;
        if (p < Lseq && !mk[k]) out_attn[(size_t)b * Lseq + p] = 0.f;
    }
    for (int e = lane; e < cnt; e += 64) {
        const float a = __expf(clog[wv][e] - m) * inv_s;
        out_attn[(size_t)b * Lseq + cpos[wv][e]] = a;
    }
}

extern "C" void kernel_launch(void* const* d_in, const int* in_sizes, int n_in,
                              void* d_out, int out_size, void* d_ws, size_t ws_size,
                              hipStream_t stream) {
    const int*   items  = (const int*)  d_in[0];  // [B,L]
    const int*   dts    = (const int*)  d_in[1];  // [B,L]
    const int*   mask   = (const int*)  d_in[2];  // [B,L]
    const int*   cand   = (const int*)  d_in[3];  // [B]
    const float* emb    = (const float*)d_in[4];  // [VOCAB,64]
    const float* gate   = (const float*)d_in[5];  // [128,1]
    const float* rawtau = (const float*)d_in[6];  // [1]

    float* out_u    = (float*)d_out;                       // B*64
    float* out_attn = out_u + Bsz * Dim;                   // B*200
    float* out_tau  = out_attn + Bsz * Lseq;               // 1

    cac_kernel<<<Bsz / WPB, 256, 0, stream>>>(items, dts, mask, cand, emb, gate,
                                              rawtau, out_u, out_attn, out_tau);
}